// Round 1
// baseline (254.787 us; speedup 1.0000x reference)
//
#include <hip/hip_runtime.h>
#include <math.h>

// Problem constants (match reference setup_inputs)
constexpr int B = 16, H = 512, W = 512;
constexpr int NPIX = B * H * W;           // 4,194,304
constexpr int BLK = 256;
constexpr int NBLK2 = NPIX / BLK;         // 16384 (exact)

#define ALPHA_C 0.5
#define BETA_C 0.5
#define SMOOTH_C 1e-06
#define BIGV 1000000.0f

// ---------------------------------------------------------------------------
// Phase 1: per-row 1D distance (fwd+bwd scan), squared. One thread per row.
// g2a: distance^2 to nearest target==1 along W
// g2b: distance^2 to nearest target==0 along W
// Exactly replicates: d = where(mask, 0, prev+1), init BIG; g = min(fwd,bwd); g*g
// ---------------------------------------------------------------------------
__global__ void rowdist_kernel(const int* __restrict__ tgt,
                               float* __restrict__ g2a,
                               float* __restrict__ g2b) {
    int rid = blockIdx.x * blockDim.x + threadIdx.x;  // b*H + h
    if (rid >= B * H) return;
    size_t base = (size_t)rid * W;

    float da = BIGV, db = BIGV;
    for (int w = 0; w < W; ++w) {
        bool m = tgt[base + w] > 0;
        da = m ? 0.0f : da + 1.0f;
        db = m ? db + 1.0f : 0.0f;
        g2a[base + w] = da;   // stash fwd distance temporarily
        g2b[base + w] = db;
    }
    da = BIGV; db = BIGV;
    for (int w = W - 1; w >= 0; --w) {
        bool m = tgt[base + w] > 0;
        da = m ? 0.0f : da + 1.0f;
        db = m ? db + 1.0f : 0.0f;
        float ga = fminf(g2a[base + w], da);
        float gb = fminf(g2b[base + w], db);
        g2a[base + w] = ga * ga;
        g2b[base + w] = gb * gb;
    }
}

// ---------------------------------------------------------------------------
// Wave/block reduction helpers (deterministic trees, no atomics)
// ---------------------------------------------------------------------------
__device__ inline double wave_reduce(double v) {
    #pragma unroll
    for (int off = 32; off > 0; off >>= 1)
        v += __shfl_down(v, off, 64);
    return v;
}

// ---------------------------------------------------------------------------
// Phase 2: column lower-envelope via expanding-ring early-exit search,
// fused with sigmoid + loss partial sums. One thread per pixel.
// d2[i] = min_{i'} ( (i-i')^2 + g2[i'] )  -- exact: any r with r^2 >= best
// cannot improve, so stop there. All f32 math here is exact (< 2^24).
// ---------------------------------------------------------------------------
__global__ void __launch_bounds__(BLK)
edt_loss_kernel(const float* __restrict__ logits,
                const int* __restrict__ tgt,
                const float* __restrict__ g2a,
                const float* __restrict__ g2b,
                double* __restrict__ partials) {
    int idx = blockIdx.x * blockDim.x + threadIdx.x;  // pixel id, < NPIX
    int w = idx & (W - 1);
    int i = (idx >> 9) & (H - 1);   // W = 512 = 2^9
    int b = idx >> 18;              // H*W = 2^18

    const float* cola = g2a + (size_t)b * H * W + w;
    const float* colb = g2b + (size_t)b * H * W + w;

    float best_a = cola[(size_t)i * W];
    float best_b = colb[(size_t)i * W];

    for (int r = 1; r < H; ++r) {
        float rr = (float)(r * r);
        if (rr >= best_a && rr >= best_b) break;
        int iu = i - r, id = i + r;
        if (iu >= 0) {
            best_a = fminf(best_a, rr + cola[(size_t)iu * W]);
            best_b = fminf(best_b, rr + colb[(size_t)iu * W]);
        }
        if (id < H) {
            best_a = fminf(best_a, rr + cola[(size_t)id * W]);
            best_b = fminf(best_b, rr + colb[(size_t)id * W]);
        }
    }

    float dist = sqrtf(best_a) + sqrtf(best_b);
    float x = logits[idx];
    float p = 1.0f / (1.0f + expf(-x));
    float tf = (float)tgt[idx];

    double v_pd = (double)(p * dist);
    double v_p  = (double)p;
    double v_t  = (double)tf;
    double v_pt = (double)(p * tf);

    v_pd = wave_reduce(v_pd);
    v_p  = wave_reduce(v_p);
    v_t  = wave_reduce(v_t);
    v_pt = wave_reduce(v_pt);

    __shared__ double sh[4][4];
    int wid = threadIdx.x >> 6, lane = threadIdx.x & 63;
    if (lane == 0) {
        sh[wid][0] = v_pd; sh[wid][1] = v_p; sh[wid][2] = v_t; sh[wid][3] = v_pt;
    }
    __syncthreads();
    if (threadIdx.x == 0) {
        double* out = partials + (size_t)blockIdx.x * 4;
        out[0] = sh[0][0] + sh[1][0] + sh[2][0] + sh[3][0];
        out[1] = sh[0][1] + sh[1][1] + sh[2][1] + sh[3][1];
        out[2] = sh[0][2] + sh[1][2] + sh[2][2] + sh[3][2];
        out[3] = sh[0][3] + sh[1][3] + sh[2][3] + sh[3][3];
    }
}

// ---------------------------------------------------------------------------
// Finalize: reduce NBLK2 partial quads, compute scalar loss.
// ---------------------------------------------------------------------------
__global__ void finalize_kernel(const double* __restrict__ partials,
                                float* __restrict__ out) {
    double a0 = 0.0, a1 = 0.0, a2 = 0.0, a3 = 0.0;
    for (int j = threadIdx.x; j < NBLK2; j += BLK) {
        const double* p = partials + (size_t)j * 4;
        a0 += p[0]; a1 += p[1]; a2 += p[2]; a3 += p[3];
    }
    a0 = wave_reduce(a0);
    a1 = wave_reduce(a1);
    a2 = wave_reduce(a2);
    a3 = wave_reduce(a3);

    __shared__ double sh[4][4];
    int wid = threadIdx.x >> 6, lane = threadIdx.x & 63;
    if (lane == 0) {
        sh[wid][0] = a0; sh[wid][1] = a1; sh[wid][2] = a2; sh[wid][3] = a3;
    }
    __syncthreads();
    if (threadIdx.x == 0) {
        double sum_pd = sh[0][0] + sh[1][0] + sh[2][0] + sh[3][0];
        double sum_p  = sh[0][1] + sh[1][1] + sh[2][1] + sh[3][1];
        double sum_t  = sh[0][2] + sh[1][2] + sh[2][2] + sh[3][2];
        double sum_pt = sh[0][3] + sh[1][3] + sh[2][3] + sh[3][3];

        double mean_pd = sum_pd / (double)NPIX;
        double loss_b = BETA_C * mean_pd;
        double dice = (2.0 * sum_pt + SMOOTH_C) / (sum_p + sum_t + SMOOTH_C);
        double loss_d = 1.0 - dice;
        out[0] = (float)(ALPHA_C * loss_d + BETA_C * loss_b);
    }
}

// ---------------------------------------------------------------------------
extern "C" void kernel_launch(void* const* d_in, const int* in_sizes, int n_in,
                              void* d_out, int out_size, void* d_ws, size_t ws_size,
                              hipStream_t stream) {
    const float* logits = (const float*)d_in[0];   // [16,1,512,512] f32
    const int* tgt      = (const int*)d_in[1];     // [16,1,512,512] i32 (0/1)
    float* out = (float*)d_out;                    // scalar

    // Workspace layout:
    //   [0, 512KB)                : double partials[NBLK2][4]
    //   [512KB, 512KB+16.78MB)    : float g2a[NPIX]
    //   [.., +16.78MB)            : float g2b[NPIX]
    double* partials = (double*)d_ws;
    float* g2a = (float*)((char*)d_ws + (size_t)NBLK2 * 4 * sizeof(double));
    float* g2b = g2a + NPIX;

    rowdist_kernel<<<(B * H + BLK - 1) / BLK, BLK, 0, stream>>>(tgt, g2a, g2b);
    edt_loss_kernel<<<NBLK2, BLK, 0, stream>>>(logits, tgt, g2a, g2b, partials);
    finalize_kernel<<<1, BLK, 0, stream>>>(partials, out);
}

// Round 2
// 74.675 us; speedup vs baseline: 3.4119x; 3.4119x over previous
//
#include <hip/hip_runtime.h>
#include <math.h>

// Problem constants (match reference setup_inputs)
constexpr int B = 16, H = 512, W = 512;
constexpr int NPIX = B * H * W;           // 4,194,304
constexpr int BLK = 256;
constexpr int NBLK2 = NPIX / BLK;         // 16384 (exact)

#define ALPHA_C 0.5
#define BETA_C 0.5
#define SMOOTH_C 1e-06
#define BIGV 1000000.0f

// ---------------------------------------------------------------------------
// Phase 1 (v2): per-row 1D distance^2 via wave-parallel max/min scans.
// One wave (64 lanes) per row; each lane owns 8 contiguous pixels.
//
//   d_fwd[w] = w - max_{w'<=w} key_f[w'],  key_f = mask ? w' : -(BIG+1)
//   d_bwd[w] = min_{w'>=w} key_b[w'] - w,  key_b = mask ? w' : W+BIG
//   g = min(d_fwd, d_bwd); store g*g
//
// All intermediate values <= 1,000,512 < 2^24: exact in f32, so results are
// bitwise identical to the reference scan recurrence.
// ---------------------------------------------------------------------------
__global__ void __launch_bounds__(256)
rowdist_kernel(const int* __restrict__ tgt,
               float* __restrict__ g2a,
               float* __restrict__ g2b) {
    const int lane = threadIdx.x & 63;
    const int row  = blockIdx.x * 4 + (threadIdx.x >> 6);   // 4 waves/block
    const size_t base = (size_t)row * W + (size_t)lane * 8;

    const int4 t0 = *reinterpret_cast<const int4*>(tgt + base);
    const int4 t1 = *reinterpret_cast<const int4*>(tgt + base + 4);
    bool m[8] = { t0.x > 0, t0.y > 0, t0.z > 0, t0.w > 0,
                  t1.x > 0, t1.y > 0, t1.z > 0, t1.w > 0 };

    const float NEG = -(BIGV + 1.0f);      // identity: no true seen yet (fwd)
    const float POS = (float)W + BIGV;     // identity: no true ahead (bwd)
    const float wbase = (float)(lane * 8);

    // ---- lane-local totals ----
    float la = NEG, lb = NEG;   // last true / false index within chunk
    float ra = POS, rb = POS;   // first true / false index within chunk
    #pragma unroll
    for (int j = 0; j < 8; ++j) {
        float w = wbase + (float)j;
        if (m[j]) la = w; else lb = w;
    }
    #pragma unroll
    for (int j = 7; j >= 0; --j) {
        float w = wbase + (float)j;
        if (m[j]) ra = w; else rb = w;
    }

    // ---- wave-level inclusive max-scan (prefix) ----
    float sa = la, sb = lb;
    #pragma unroll
    for (int off = 1; off < 64; off <<= 1) {
        float ua = __shfl_up(sa, off, 64);
        float ub = __shfl_up(sb, off, 64);
        if (lane >= off) { sa = fmaxf(sa, ua); sb = fmaxf(sb, ub); }
    }
    float carry_a = __shfl_up(sa, 1, 64); if (lane == 0) carry_a = NEG;
    float carry_b = __shfl_up(sb, 1, 64); if (lane == 0) carry_b = NEG;

    // ---- wave-level inclusive min-scan (suffix) ----
    float ta = ra, tb = rb;
    #pragma unroll
    for (int off = 1; off < 64; off <<= 1) {
        float ua = __shfl_down(ta, off, 64);
        float ub = __shfl_down(tb, off, 64);
        if (lane < 64 - off) { ta = fminf(ta, ua); tb = fminf(tb, ub); }
    }
    float rcarry_a = __shfl_down(ta, 1, 64); if (lane == 63) rcarry_a = POS;
    float rcarry_b = __shfl_down(tb, 1, 64); if (lane == 63) rcarry_b = POS;

    // ---- per-element distances ----
    float ga[8], gb[8];
    la = carry_a; lb = carry_b;
    #pragma unroll
    for (int j = 0; j < 8; ++j) {
        float w = wbase + (float)j;
        if (m[j]) la = w; else lb = w;
        ga[j] = w - la;
        gb[j] = w - lb;
    }
    ra = rcarry_a; rb = rcarry_b;
    #pragma unroll
    for (int j = 7; j >= 0; --j) {
        float w = wbase + (float)j;
        if (m[j]) ra = w; else rb = w;
        ga[j] = fminf(ga[j], ra - w);
        gb[j] = fminf(gb[j], rb - w);
    }

    float4 oa0 = make_float4(ga[0]*ga[0], ga[1]*ga[1], ga[2]*ga[2], ga[3]*ga[3]);
    float4 oa1 = make_float4(ga[4]*ga[4], ga[5]*ga[5], ga[6]*ga[6], ga[7]*ga[7]);
    float4 ob0 = make_float4(gb[0]*gb[0], gb[1]*gb[1], gb[2]*gb[2], gb[3]*gb[3]);
    float4 ob1 = make_float4(gb[4]*gb[4], gb[5]*gb[5], gb[6]*gb[6], gb[7]*gb[7]);
    *reinterpret_cast<float4*>(g2a + base)     = oa0;
    *reinterpret_cast<float4*>(g2a + base + 4) = oa1;
    *reinterpret_cast<float4*>(g2b + base)     = ob0;
    *reinterpret_cast<float4*>(g2b + base + 4) = ob1;
}

// ---------------------------------------------------------------------------
// Wave/block reduction helpers (deterministic trees, no atomics)
// ---------------------------------------------------------------------------
__device__ inline double wave_reduce(double v) {
    #pragma unroll
    for (int off = 32; off > 0; off >>= 1)
        v += __shfl_down(v, off, 64);
    return v;
}

// ---------------------------------------------------------------------------
// Phase 2: column lower-envelope via expanding-ring early-exit search,
// fused with sigmoid + loss partial sums. One thread per pixel.
// d2[i] = min_{i'} ( (i-i')^2 + g2[i'] )  -- exact: any r with r^2 >= best
// cannot improve, so stop there. All f32 math here is exact (< 2^24).
// ---------------------------------------------------------------------------
__global__ void __launch_bounds__(BLK)
edt_loss_kernel(const float* __restrict__ logits,
                const int* __restrict__ tgt,
                const float* __restrict__ g2a,
                const float* __restrict__ g2b,
                double* __restrict__ partials) {
    int idx = blockIdx.x * blockDim.x + threadIdx.x;  // pixel id, < NPIX
    int w = idx & (W - 1);
    int i = (idx >> 9) & (H - 1);   // W = 512 = 2^9
    int b = idx >> 18;              // H*W = 2^18

    const float* cola = g2a + (size_t)b * H * W + w;
    const float* colb = g2b + (size_t)b * H * W + w;

    float best_a = cola[(size_t)i * W];
    float best_b = colb[(size_t)i * W];

    for (int r = 1; r < H; ++r) {
        float rr = (float)(r * r);
        if (rr >= best_a && rr >= best_b) break;
        int iu = i - r, id = i + r;
        if (iu >= 0) {
            best_a = fminf(best_a, rr + cola[(size_t)iu * W]);
            best_b = fminf(best_b, rr + colb[(size_t)iu * W]);
        }
        if (id < H) {
            best_a = fminf(best_a, rr + cola[(size_t)id * W]);
            best_b = fminf(best_b, rr + colb[(size_t)id * W]);
        }
    }

    float dist = sqrtf(best_a) + sqrtf(best_b);
    float x = logits[idx];
    float p = 1.0f / (1.0f + expf(-x));
    float tf = (float)tgt[idx];

    double v_pd = (double)(p * dist);
    double v_p  = (double)p;
    double v_t  = (double)tf;
    double v_pt = (double)(p * tf);

    v_pd = wave_reduce(v_pd);
    v_p  = wave_reduce(v_p);
    v_t  = wave_reduce(v_t);
    v_pt = wave_reduce(v_pt);

    __shared__ double sh[4][4];
    int wid = threadIdx.x >> 6, lane = threadIdx.x & 63;
    if (lane == 0) {
        sh[wid][0] = v_pd; sh[wid][1] = v_p; sh[wid][2] = v_t; sh[wid][3] = v_pt;
    }
    __syncthreads();
    if (threadIdx.x == 0) {
        double* out = partials + (size_t)blockIdx.x * 4;
        out[0] = sh[0][0] + sh[1][0] + sh[2][0] + sh[3][0];
        out[1] = sh[0][1] + sh[1][1] + sh[2][1] + sh[3][1];
        out[2] = sh[0][2] + sh[1][2] + sh[2][2] + sh[3][2];
        out[3] = sh[0][3] + sh[1][3] + sh[2][3] + sh[3][3];
    }
}

// ---------------------------------------------------------------------------
// Finalize: reduce NBLK2 partial quads, compute scalar loss.
// ---------------------------------------------------------------------------
__global__ void finalize_kernel(const double* __restrict__ partials,
                                float* __restrict__ out) {
    double a0 = 0.0, a1 = 0.0, a2 = 0.0, a3 = 0.0;
    for (int j = threadIdx.x; j < NBLK2; j += BLK) {
        const double* p = partials + (size_t)j * 4;
        a0 += p[0]; a1 += p[1]; a2 += p[2]; a3 += p[3];
    }
    a0 = wave_reduce(a0);
    a1 = wave_reduce(a1);
    a2 = wave_reduce(a2);
    a3 = wave_reduce(a3);

    __shared__ double sh[4][4];
    int wid = threadIdx.x >> 6, lane = threadIdx.x & 63;
    if (lane == 0) {
        sh[wid][0] = a0; sh[wid][1] = a1; sh[wid][2] = a2; sh[wid][3] = a3;
    }
    __syncthreads();
    if (threadIdx.x == 0) {
        double sum_pd = sh[0][0] + sh[1][0] + sh[2][0] + sh[3][0];
        double sum_p  = sh[0][1] + sh[1][1] + sh[2][1] + sh[3][1];
        double sum_t  = sh[0][2] + sh[1][2] + sh[2][2] + sh[3][2];
        double sum_pt = sh[0][3] + sh[1][3] + sh[2][3] + sh[3][3];

        double mean_pd = sum_pd / (double)NPIX;
        double loss_b = BETA_C * mean_pd;
        double dice = (2.0 * sum_pt + SMOOTH_C) / (sum_p + sum_t + SMOOTH_C);
        double loss_d = 1.0 - dice;
        out[0] = (float)(ALPHA_C * loss_d + BETA_C * loss_b);
    }
}

// ---------------------------------------------------------------------------
extern "C" void kernel_launch(void* const* d_in, const int* in_sizes, int n_in,
                              void* d_out, int out_size, void* d_ws, size_t ws_size,
                              hipStream_t stream) {
    const float* logits = (const float*)d_in[0];   // [16,1,512,512] f32
    const int* tgt      = (const int*)d_in[1];     // [16,1,512,512] i32 (0/1)
    float* out = (float*)d_out;                    // scalar

    // Workspace layout:
    //   [0, 512KB)                : double partials[NBLK2][4]
    //   [512KB, ...)              : float g2a[NPIX], float g2b[NPIX]
    double* partials = (double*)d_ws;
    float* g2a = (float*)((char*)d_ws + (size_t)NBLK2 * 4 * sizeof(double));
    float* g2b = g2a + NPIX;

    rowdist_kernel<<<B * H / 4, 256, 0, stream>>>(tgt, g2a, g2b);
    edt_loss_kernel<<<NBLK2, BLK, 0, stream>>>(logits, tgt, g2a, g2b, partials);
    finalize_kernel<<<1, BLK, 0, stream>>>(partials, out);
}

// Round 3
// 55.149 us; speedup vs baseline: 4.6200x; 1.3541x over previous
//
#include <hip/hip_runtime.h>
#include <math.h>

// Problem constants (match reference setup_inputs)
constexpr int B = 16, H = 512, W = 512;
constexpr int NPIX = B * H * W;           // 4,194,304
constexpr int BLK = 256;
constexpr int PPT = 4;                    // pixels per thread (edt kernel)
constexpr int NBLK2 = NPIX / (BLK * PPT); // 4096

#define ALPHA_C 0.5
#define BETA_C 0.5
#define SMOOTH_C 1e-06
#define BIGV 1000000.0f

// ---------------------------------------------------------------------------
// Phase 1: per-row 1D distance^2 via wave-parallel max/min scans.
// One wave (64 lanes) per row; each lane owns 8 contiguous pixels.
// Exact (all values < 2^24 -> f32 integer math is exact).
// ---------------------------------------------------------------------------
__global__ void __launch_bounds__(256)
rowdist_kernel(const int* __restrict__ tgt,
               float* __restrict__ g2a,
               float* __restrict__ g2b) {
    const int lane = threadIdx.x & 63;
    const int row  = blockIdx.x * 4 + (threadIdx.x >> 6);   // 4 waves/block
    const size_t base = (size_t)row * W + (size_t)lane * 8;

    const int4 t0 = *reinterpret_cast<const int4*>(tgt + base);
    const int4 t1 = *reinterpret_cast<const int4*>(tgt + base + 4);
    bool m[8] = { t0.x > 0, t0.y > 0, t0.z > 0, t0.w > 0,
                  t1.x > 0, t1.y > 0, t1.z > 0, t1.w > 0 };

    const float NEG = -(BIGV + 1.0f);      // identity: no true seen yet (fwd)
    const float POS = (float)W + BIGV;     // identity: no true ahead (bwd)
    const float wbase = (float)(lane * 8);

    // ---- lane-local totals ----
    float la = NEG, lb = NEG;   // last 1 / 0 index within chunk
    float ra = POS, rb = POS;   // first 1 / 0 index within chunk
    #pragma unroll
    for (int j = 0; j < 8; ++j) {
        float w = wbase + (float)j;
        if (m[j]) la = w; else lb = w;
    }
    #pragma unroll
    for (int j = 7; j >= 0; --j) {
        float w = wbase + (float)j;
        if (m[j]) ra = w; else rb = w;
    }

    // ---- wave-level inclusive max-scan (prefix) ----
    float sa = la, sb = lb;
    #pragma unroll
    for (int off = 1; off < 64; off <<= 1) {
        float ua = __shfl_up(sa, off, 64);
        float ub = __shfl_up(sb, off, 64);
        if (lane >= off) { sa = fmaxf(sa, ua); sb = fmaxf(sb, ub); }
    }
    float carry_a = __shfl_up(sa, 1, 64); if (lane == 0) carry_a = NEG;
    float carry_b = __shfl_up(sb, 1, 64); if (lane == 0) carry_b = NEG;

    // ---- wave-level inclusive min-scan (suffix) ----
    float ta = ra, tb = rb;
    #pragma unroll
    for (int off = 1; off < 64; off <<= 1) {
        float ua = __shfl_down(ta, off, 64);
        float ub = __shfl_down(tb, off, 64);
        if (lane < 64 - off) { ta = fminf(ta, ua); tb = fminf(tb, ub); }
    }
    float rcarry_a = __shfl_down(ta, 1, 64); if (lane == 63) rcarry_a = POS;
    float rcarry_b = __shfl_down(tb, 1, 64); if (lane == 63) rcarry_b = POS;

    // ---- per-element distances ----
    float ga[8], gb[8];
    la = carry_a; lb = carry_b;
    #pragma unroll
    for (int j = 0; j < 8; ++j) {
        float w = wbase + (float)j;
        if (m[j]) la = w; else lb = w;
        ga[j] = w - la;
        gb[j] = w - lb;
    }
    ra = rcarry_a; rb = rcarry_b;
    #pragma unroll
    for (int j = 7; j >= 0; --j) {
        float w = wbase + (float)j;
        if (m[j]) ra = w; else rb = w;
        ga[j] = fminf(ga[j], ra - w);
        gb[j] = fminf(gb[j], rb - w);
    }

    float4 oa0 = make_float4(ga[0]*ga[0], ga[1]*ga[1], ga[2]*ga[2], ga[3]*ga[3]);
    float4 oa1 = make_float4(ga[4]*ga[4], ga[5]*ga[5], ga[6]*ga[6], ga[7]*ga[7]);
    float4 ob0 = make_float4(gb[0]*gb[0], gb[1]*gb[1], gb[2]*gb[2], gb[3]*gb[3]);
    float4 ob1 = make_float4(gb[4]*gb[4], gb[5]*gb[5], gb[6]*gb[6], gb[7]*gb[7]);
    *reinterpret_cast<float4*>(g2a + base)     = oa0;
    *reinterpret_cast<float4*>(g2a + base + 4) = oa1;
    *reinterpret_cast<float4*>(g2b + base)     = ob0;
    *reinterpret_cast<float4*>(g2b + base + 4) = ob1;
}

// ---------------------------------------------------------------------------
__device__ inline double wave_reduce(double v) {
    #pragma unroll
    for (int off = 32; off > 0; off >>= 1)
        v += __shfl_down(v, off, 64);
    return v;
}

// ---------------------------------------------------------------------------
// Phase 2: per pixel, dist = sqrt of column-envelope min of the OPPOSITE
// class only (own-class EDT is exactly 0 at the pixel). Straight-line
// window r=0..3 (7 independent loads, full MLP), rare tail loop beyond.
// All arithmetic exact (integers < 2^24 in f32); min is order-independent,
// so results are bitwise identical to the reference.
// ---------------------------------------------------------------------------
__global__ void __launch_bounds__(BLK)
edt_loss_kernel(const float* __restrict__ logits,
                const int* __restrict__ tgt,
                const float* __restrict__ g2a,
                const float* __restrict__ g2b,
                double* __restrict__ partials) {
    const int tid  = blockIdx.x * BLK + threadIdx.x;
    const int pix0 = tid * PPT;                 // 4 consecutive pixels, same row
    const int w0 = pix0 & (W - 1);
    const int i  = (pix0 >> 9) & (H - 1);       // W = 2^9
    const int b  = pix0 >> 18;                  // H*W = 2^18

    const float4 lg = *reinterpret_cast<const float4*>(logits + pix0);
    const int4   tg = *reinterpret_cast<const int4*>(tgt + pix0);
    const float* basea = g2a + (size_t)b * H * W;
    const float* baseb = g2b + (size_t)b * H * W;

    const int   tv[4] = { tg.x, tg.y, tg.z, tg.w };
    const float xv[4] = { lg.x, lg.y, lg.z, lg.w };

    float best[4];
    const float* col[4];
    #pragma unroll
    for (int k = 0; k < 4; ++k) {
        // search the opposite-class distance field
        col[k] = (tv[k] > 0 ? baseb : basea) + (w0 + k);
        best[k] = col[k][(size_t)i * W];        // r = 0
    }
    // straight-line window r = 1..3: independent loads, then mins
    #pragma unroll
    for (int r = 1; r <= 3; ++r) {
        const float rr = (float)(r * r);
        const int iu = i - r, id = i + r;
        #pragma unroll
        for (int k = 0; k < 4; ++k) {
            float vu = (iu >= 0) ? col[k][(size_t)iu * W] : 1e30f;
            float vd = (id <  H) ? col[k][(size_t)id * W] : 1e30f;
            best[k] = fminf(best[k], fminf(vu, vd) + rr);
        }
    }
    // rare tail: only if some best still exceeds 4^2
    #pragma unroll
    for (int k = 0; k < 4; ++k) {
        if (16.0f < best[k]) {
            for (int r = 4; r < H; ++r) {
                const float rr = (float)(r * r);
                if (rr >= best[k]) break;
                const int iu = i - r, id = i + r;
                if (iu >= 0) best[k] = fminf(best[k], rr + col[k][(size_t)iu * W]);
                if (id <  H) best[k] = fminf(best[k], rr + col[k][(size_t)id * W]);
            }
        }
    }

    double v_pd = 0.0, v_p = 0.0, v_t = 0.0, v_pt = 0.0;
    #pragma unroll
    for (int k = 0; k < 4; ++k) {
        const float dist = sqrtf(best[k]);      // own-class term is exactly 0
        const float p = 1.0f / (1.0f + expf(-xv[k]));
        const float tf = (float)tv[k];
        v_pd += (double)(p * dist);
        v_p  += (double)p;
        v_t  += (double)tf;
        v_pt += (double)(p * tf);
    }

    v_pd = wave_reduce(v_pd);
    v_p  = wave_reduce(v_p);
    v_t  = wave_reduce(v_t);
    v_pt = wave_reduce(v_pt);

    __shared__ double sh[4][4];
    const int wid = threadIdx.x >> 6, lane = threadIdx.x & 63;
    if (lane == 0) {
        sh[wid][0] = v_pd; sh[wid][1] = v_p; sh[wid][2] = v_t; sh[wid][3] = v_pt;
    }
    __syncthreads();
    if (threadIdx.x == 0) {
        double* out = partials + (size_t)blockIdx.x * 4;
        out[0] = sh[0][0] + sh[1][0] + sh[2][0] + sh[3][0];
        out[1] = sh[0][1] + sh[1][1] + sh[2][1] + sh[3][1];
        out[2] = sh[0][2] + sh[1][2] + sh[2][2] + sh[3][2];
        out[3] = sh[0][3] + sh[1][3] + sh[2][3] + sh[3][3];
    }
}

// ---------------------------------------------------------------------------
// Finalize: reduce NBLK2 partial quads, compute scalar loss.
// ---------------------------------------------------------------------------
__global__ void finalize_kernel(const double* __restrict__ partials,
                                float* __restrict__ out) {
    double a0 = 0.0, a1 = 0.0, a2 = 0.0, a3 = 0.0;
    for (int j = threadIdx.x; j < NBLK2; j += BLK) {
        const double* p = partials + (size_t)j * 4;
        a0 += p[0]; a1 += p[1]; a2 += p[2]; a3 += p[3];
    }
    a0 = wave_reduce(a0);
    a1 = wave_reduce(a1);
    a2 = wave_reduce(a2);
    a3 = wave_reduce(a3);

    __shared__ double sh[4][4];
    const int wid = threadIdx.x >> 6, lane = threadIdx.x & 63;
    if (lane == 0) {
        sh[wid][0] = a0; sh[wid][1] = a1; sh[wid][2] = a2; sh[wid][3] = a3;
    }
    __syncthreads();
    if (threadIdx.x == 0) {
        double sum_pd = sh[0][0] + sh[1][0] + sh[2][0] + sh[3][0];
        double sum_p  = sh[0][1] + sh[1][1] + sh[2][1] + sh[3][1];
        double sum_t  = sh[0][2] + sh[1][2] + sh[2][2] + sh[3][2];
        double sum_pt = sh[0][3] + sh[1][3] + sh[2][3] + sh[3][3];

        double mean_pd = sum_pd / (double)NPIX;
        double loss_b = BETA_C * mean_pd;
        double dice = (2.0 * sum_pt + SMOOTH_C) / (sum_p + sum_t + SMOOTH_C);
        double loss_d = 1.0 - dice;
        out[0] = (float)(ALPHA_C * loss_d + BETA_C * loss_b);
    }
}

// ---------------------------------------------------------------------------
extern "C" void kernel_launch(void* const* d_in, const int* in_sizes, int n_in,
                              void* d_out, int out_size, void* d_ws, size_t ws_size,
                              hipStream_t stream) {
    const float* logits = (const float*)d_in[0];   // [16,1,512,512] f32
    const int* tgt      = (const int*)d_in[1];     // [16,1,512,512] i32 (0/1)
    float* out = (float*)d_out;                    // scalar

    // Workspace layout:
    //   [0, 512KB)   : double partials[NBLK2][4]  (only 128KB used)
    //   [512KB, ...) : float g2a[NPIX], float g2b[NPIX]
    double* partials = (double*)d_ws;
    float* g2a = (float*)((char*)d_ws + (size_t)512 * 1024);
    float* g2b = g2a + NPIX;

    rowdist_kernel<<<B * H / 4, 256, 0, stream>>>(tgt, g2a, g2b);
    edt_loss_kernel<<<NBLK2, BLK, 0, stream>>>(logits, tgt, g2a, g2b, partials);
    finalize_kernel<<<1, BLK, 0, stream>>>(partials, out);
}